// Round 3
// baseline (312.413 us; speedup 1.0000x reference)
//
#include <hip/hip_runtime.h>
#include <hip/hip_bf16.h>
#include <stdint.h>

#define H 128
#define NNODES 100000
#define NEDGE 500000
#define MT 64  // node rows per GEMM block

// ws layout:
//   [0, 65536)        : Bsw  bf16, fragment-swizzled w1 (16 kb-groups x 256 cols x 8)
//   [65536, +25.6MB)x4: T_ps, T_pd, T_os, T_od  bf16 [100000][128]
#define BSW_BYTES 65536
#define TBL_ELEMS (NNODES * H)
#define WS_NEEDED ((size_t)BSW_BYTES + 4ULL * TBL_ELEMS * 2ULL)

typedef __bf16 bf16x8 __attribute__((ext_vector_type(8)));
typedef float f32x4 __attribute__((ext_vector_type(4)));

union frag_cast { uint4 u; bf16x8 b; ushort s[8]; };

#define EPI_STRIDE 260  // 256 + 4 ushorts pad: 4-row quad offset = 8 banks, conflict-free

__device__ __forceinline__ ushort f2bf(float f) {
    __hip_bfloat16 h = __float2bfloat16(f);
    return *(ushort*)&h;
}

__device__ __forceinline__ void bf2_to_f(uint32_t u, float& lo, float& hi) {
    union { uint32_t i; float f; } a, b;
    a.i = u << 16;
    b.i = u & 0xffff0000u;
    lo = a.f;
    hi = b.f;
}

// Build fragment-swizzled bf16 B from w1.
// Bsw element i: j=i&7, n=(i>>3)&255, kb=i>>11; k=kb*8+j;
// B[k][n] = (n<128) ? w1[k][n] : w1[128+k][n-128]
__global__ __launch_bounds__(256) void prep_bsw(const float* __restrict__ w1,
                                                ushort* __restrict__ bsw) {
    int i = blockIdx.x * 256 + threadIdx.x;  // 0..32767
    int j = i & 7;
    int n = (i >> 3) & 255;
    int kb = i >> 11;
    int k = kb * 8 + j;
    int r = (n < 128) ? k : (128 + k);
    int c = n & 127;
    bsw[i] = f2bf(w1[r * H + c]);
}

// GEMM: [64 rows, K=128] x [128, 256] -> bf16 tables, one tile per block.
// 512 threads = 8 waves: wave>>2 = row half (32 rows), wave&3 = col group (64).
// A: global fp32 -> registers -> bf16 (no LDS). B: preloaded fragments (L2-hot).
// blockIdx.y: 0 = zp -> (t_ps|t_pd), 1 = zo -> (t_os|t_od)
__global__ __launch_bounds__(512) void gemm_tables(
    const float* __restrict__ zp, const float* __restrict__ zo,
    const ushort* __restrict__ bsw, const float* __restrict__ b1,
    ushort* __restrict__ t_ps, ushort* __restrict__ t_pd,
    ushort* __restrict__ t_os, ushort* __restrict__ t_od) {
    __shared__ ushort lds[MT * EPI_STRIDE];  // epilogue staging, 33.3 KB

    const int t = threadIdx.x;
    const int wave = t >> 6;
    const int lane = t & 63;
    const int l15 = lane & 15;
    const int quad = lane >> 4;
    const int R0 = (wave >> 2) * 32;   // local row base for this wave
    const int col0 = (wave & 3) * 64;  // output col base for this wave

    const int node0 = blockIdx.x * MT;
    const int zsel = blockIdx.y;
    const float* __restrict__ z = zsel ? zo : zp;

    // ---- Preload B fragments: [s][nt], 16 x 16B, L2-hot after first blocks ----
    frag_cast bfr[4][4];
#pragma unroll
    for (int s = 0; s < 4; ++s)
#pragma unroll
        for (int nt = 0; nt < 4; ++nt) {
            const int kb = s * 4 + quad;
            const int n = col0 + nt * 16 + l15;
            bfr[s][nt].u = *(const uint4*)(bsw + (kb * 256 + n) * 8);
        }

    f32x4 acc[2][4];
#pragma unroll
    for (int mt = 0; mt < 2; ++mt)
#pragma unroll
        for (int nt = 0; nt < 4; ++nt)
            acc[mt][nt] = (f32x4){0.f, 0.f, 0.f, 0.f};

    // ---- Main: K=128, A straight from global (row-major slice = A fragment) ----
#pragma unroll
    for (int s = 0; s < 4; ++s) {
#pragma unroll
        for (int mt = 0; mt < 2; ++mt) {
            int row_node = node0 + R0 + mt * 16 + l15;
            if (row_node >= NNODES) row_node = NNODES - 1;  // tail clamp (dup read)
            const float* p = z + (size_t)row_node * H + s * 32 + quad * 8;
            const float4 v0 = *(const float4*)p;
            const float4 v1 = *(const float4*)(p + 4);
            frag_cast a;
            a.s[0] = f2bf(v0.x); a.s[1] = f2bf(v0.y);
            a.s[2] = f2bf(v0.z); a.s[3] = f2bf(v0.w);
            a.s[4] = f2bf(v1.x); a.s[5] = f2bf(v1.y);
            a.s[6] = f2bf(v1.z); a.s[7] = f2bf(v1.w);
#pragma unroll
            for (int nt = 0; nt < 4; ++nt)
                acc[mt][nt] = __builtin_amdgcn_mfma_f32_16x16x32_bf16(
                    a.b, bfr[s][nt].b, acc[mt][nt], 0, 0, 0);
        }
    }

    // ---- Bias (cols >= 128, wave-uniform branch) ----
    float bias[4] = {0.f, 0.f, 0.f, 0.f};
    if ((wave & 3) >= 2) {
#pragma unroll
        for (int nt = 0; nt < 4; ++nt)
            bias[nt] = b1[(col0 - 128) + nt * 16 + l15];
    }

    // ---- Epilogue: acc -> LDS bf16 (D: col=l15, row=quad*4+reg) ----
#pragma unroll
    for (int mt = 0; mt < 2; ++mt)
#pragma unroll
        for (int nt = 0; nt < 4; ++nt)
#pragma unroll
            for (int r = 0; r < 4; ++r) {
                const int row = R0 + mt * 16 + quad * 4 + r;
                const int col = col0 + nt * 16 + l15;
                lds[row * EPI_STRIDE + col] = f2bf(acc[mt][nt][r] + bias[nt]);
            }
    __syncthreads();

    // ---- Coalesced store: cols 0..127 -> t_s, 128..255 -> t_d ----
    const int table = t >> 8;  // 0 = s-table, 1 = d-table
    const int tt = t & 255;
    const int row = tt >> 2;        // 0..63
    const int cbase = (tt & 3) * 32;
    if (node0 + row < NNODES) {
        ushort* __restrict__ dst =
            zsel ? (table ? t_od : t_os) : (table ? t_pd : t_ps);
        const size_t obase = (size_t)(node0 + row) * H + cbase;
        const int lbase = row * EPI_STRIDE + table * 128 + cbase;
#pragma unroll
        for (int q = 0; q < 4; ++q)
            *(uint4*)(dst + obase + q * 8) = *(const uint4*)(lds + lbase + q * 8);
    }
}

// 16 lanes per edge; each lane handles 8 channels (16B bf16 loads).
__global__ __launch_bounds__(256) void edge_kernel(
    const __hip_bfloat16* __restrict__ t_ps, const __hip_bfloat16* __restrict__ t_pd,
    const __hip_bfloat16* __restrict__ t_os, const __hip_bfloat16* __restrict__ t_od,
    const int* __restrict__ ptnp, const int* __restrict__ nptp,
    const int* __restrict__ nptnp,
    const float* __restrict__ w2, const float* __restrict__ b2,
    float* __restrict__ out) {
    const int tid = blockIdx.x * 256 + threadIdx.x;
    const int g = tid >> 4;        // edge id 0..3E-1
    const int lane = tid & 15;

    const __hip_bfloat16 *src_tbl, *dst_tbl;
    int si, di;
    if (g < NEDGE) {
        si = ptnp[g]; di = ptnp[NEDGE + g];
        src_tbl = t_ps; dst_tbl = t_od;
    } else if (g < 2 * NEDGE) {
        const int e = g - NEDGE;
        si = nptp[e]; di = nptp[NEDGE + e];
        src_tbl = t_os; dst_tbl = t_pd;
    } else {
        const int e = g - 2 * NEDGE;
        si = nptnp[e]; di = nptnp[NEDGE + e];
        src_tbl = t_os; dst_tbl = t_od;
    }

    const uint4 s4 = *(const uint4*)(src_tbl + si * H + lane * 8);
    const uint4 d4 = *(const uint4*)(dst_tbl + di * H + lane * 8);
    const float4 w2a = *(const float4*)(w2 + lane * 8);
    const float4 w2b = *(const float4*)(w2 + lane * 8 + 4);

    float s0, s1, d0, d1;
    float sum = 0.f;
    bf2_to_f(s4.x, s0, s1); bf2_to_f(d4.x, d0, d1);
    sum = fmaf(fmaxf(s0 + d0, 0.f), w2a.x, sum);
    sum = fmaf(fmaxf(s1 + d1, 0.f), w2a.y, sum);
    bf2_to_f(s4.y, s0, s1); bf2_to_f(d4.y, d0, d1);
    sum = fmaf(fmaxf(s0 + d0, 0.f), w2a.z, sum);
    sum = fmaf(fmaxf(s1 + d1, 0.f), w2a.w, sum);
    bf2_to_f(s4.z, s0, s1); bf2_to_f(d4.z, d0, d1);
    sum = fmaf(fmaxf(s0 + d0, 0.f), w2b.x, sum);
    sum = fmaf(fmaxf(s1 + d1, 0.f), w2b.y, sum);
    bf2_to_f(s4.w, s0, s1); bf2_to_f(d4.w, d0, d1);
    sum = fmaf(fmaxf(s0 + d0, 0.f), w2b.z, sum);
    sum = fmaf(fmaxf(s1 + d1, 0.f), w2b.w, sum);

    sum += __shfl_down(sum, 8, 16);
    sum += __shfl_down(sum, 4, 16);
    sum += __shfl_down(sum, 2, 16);
    sum += __shfl_down(sum, 1, 16);
    if (lane == 0) out[g] = sum + b2[0];
}

// Fallback (only if ws_size is too small): direct per-edge compute, fp32.
__global__ __launch_bounds__(128) void edge_direct(
    const float* __restrict__ zp, const float* __restrict__ zo,
    const int* __restrict__ ptnp, const int* __restrict__ nptp,
    const int* __restrict__ nptnp,
    const float* __restrict__ w1, const float* __restrict__ b1,
    const float* __restrict__ w2, const float* __restrict__ b2,
    float* __restrict__ out) {
    const int g = blockIdx.x;
    const int j = threadIdx.x;

    const float *src, *dst;
    int si, di;
    if (g < NEDGE) {
        si = ptnp[g]; di = ptnp[NEDGE + g]; src = zp; dst = zo;
    } else if (g < 2 * NEDGE) {
        const int e = g - NEDGE;
        si = nptp[e]; di = nptp[NEDGE + e]; src = zo; dst = zp;
    } else {
        const int e = g - 2 * NEDGE;
        si = nptnp[e]; di = nptnp[NEDGE + e]; src = zo; dst = zo;
    }
    const float* zs = src + si * H;
    const float* zd = dst + di * H;

    float acc = b1[j];
    for (int k = 0; k < H; ++k) acc = fmaf(zs[k], w1[k * H + j], acc);
    for (int k = 0; k < H; ++k) acc = fmaf(zd[k], w1[(H + k) * H + j], acc);
    float v = fmaxf(acc, 0.f) * w2[j];

    for (int off = 32; off > 0; off >>= 1) v += __shfl_down(v, off, 64);
    __shared__ float parts[2];
    if ((j & 63) == 0) parts[j >> 6] = v;
    __syncthreads();
    if (j == 0) out[g] = parts[0] + parts[1] + b2[0];
}

extern "C" void kernel_launch(void* const* d_in, const int* in_sizes, int n_in,
                              void* d_out, int out_size, void* d_ws, size_t ws_size,
                              hipStream_t stream) {
    const float* zp    = (const float*)d_in[0];
    const float* zo    = (const float*)d_in[1];
    const int*   ptnp  = (const int*)d_in[2];
    const int*   nptp  = (const int*)d_in[3];
    const int*   nptnp = (const int*)d_in[4];
    const float* w1    = (const float*)d_in[5];
    const float* b1    = (const float*)d_in[6];
    const float* w2    = (const float*)d_in[7];
    const float* b2    = (const float*)d_in[8];
    float* out = (float*)d_out;

    if (ws_size < WS_NEEDED) {
        edge_direct<<<3 * NEDGE, 128, 0, stream>>>(zp, zo, ptnp, nptp, nptnp,
                                                   w1, b1, w2, b2, out);
        return;
    }

    char* ws = (char*)d_ws;
    ushort* bsw = (ushort*)ws;
    ushort* t_ps = (ushort*)(ws + BSW_BYTES);
    ushort* t_pd = t_ps + TBL_ELEMS;
    ushort* t_os = t_pd + TBL_ELEMS;
    ushort* t_od = t_os + TBL_ELEMS;

    prep_bsw<<<128, 256, 0, stream>>>(w1, bsw);

    const int gx = (NNODES + MT - 1) / MT;  // 1563 (last block tail-guarded)
    gemm_tables<<<dim3(gx, 2), 512, 0, stream>>>(
        zp, zo, bsw, b1, t_ps, t_pd, t_os, t_od);

    const int total_threads = 3 * NEDGE * 16;
    edge_kernel<<<total_threads / 256, 256, 0, stream>>>(
        (const __hip_bfloat16*)t_ps, (const __hip_bfloat16*)t_pd,
        (const __hip_bfloat16*)t_os, (const __hip_bfloat16*)t_od,
        ptnp, nptp, nptnp, w2, b2, out);
}

// Round 4
// 270.467 us; speedup vs baseline: 1.1551x; 1.1551x over previous
//
#include <hip/hip_runtime.h>
#include <hip/hip_bf16.h>
#include <stdint.h>

#define H 128
#define NNODES 100000
#define NEDGE 500000
#define MT 32                 // node rows per GEMM tile (100000 = 3125 * 32, exact)
#define TILES_PER_Z 3125
#define GEMM_GRID 1024

// ws layout:
//   [0, 65536)        : Bsw  bf16, fragment-swizzled w1 (16 kb-groups x 256 cols x 8)
//   [65536, +25.6MB)x4: T_ps, T_pd, T_os, T_od  bf16 [100000][128]
#define BSW_BYTES 65536
#define TBL_ELEMS (NNODES * H)
#define WS_NEEDED ((size_t)BSW_BYTES + 4ULL * TBL_ELEMS * 2ULL)

typedef __bf16 bf16x8 __attribute__((ext_vector_type(8)));
typedef float f32x4 __attribute__((ext_vector_type(4)));

union frag_cast { uint4 u; bf16x8 b; ushort s[8]; };

__device__ __forceinline__ ushort f2bf(float f) {
    __hip_bfloat16 h = __float2bfloat16(f);
    return *(ushort*)&h;
}

__device__ __forceinline__ void bf2_to_f(uint32_t u, float& lo, float& hi) {
    union { uint32_t i; float f; } a, b;
    a.i = u << 16;
    b.i = u & 0xffff0000u;
    lo = a.f;
    hi = b.f;
}

// Build fragment-swizzled bf16 B from w1.
// Bsw element i: j=i&7, n=(i>>3)&255, kb=i>>11; k=kb*8+j;
// B[k][n] = (n<128) ? w1[k][n] : w1[128+k][n-128]
__global__ __launch_bounds__(256) void prep_bsw(const float* __restrict__ w1,
                                                ushort* __restrict__ bsw) {
    int i = blockIdx.x * 256 + threadIdx.x;  // 0..32767
    int j = i & 7;
    int n = (i >> 3) & 255;
    int kb = i >> 11;
    int k = kb * 8 + j;
    int r = (n < 128) ? k : (128 + k);
    int c = n & 127;
    bsw[i] = f2bf(w1[r * H + c]);
}

// Persistent GEMM: grid-stride over 6250 tiles of [32 rows, K=128] x [128, 256].
// 256 threads = 4 waves; wave w owns output cols [w*64, w*64+64).
// B fragments + bias loaded ONCE per block. A staged fp32 -> LDS via
// global_load_lds (16B), with source-index XOR swizzle so ds_read_b128
// fragment reads are <=2-way banked (free). Stores: 2B per-lane, rows of 16
// consecutive cols per quad -> 4x32B segments/instr, L2 write-combined.
__global__ __launch_bounds__(256, 3) void gemm_tables(
    const float* __restrict__ zp, const float* __restrict__ zo,
    const ushort* __restrict__ bsw, const float* __restrict__ b1,
    ushort* __restrict__ t_ps, ushort* __restrict__ t_pd,
    ushort* __restrict__ t_os, ushort* __restrict__ t_od) {
    __shared__ float abuf[MT * H];  // 16 KB; abuf[row][j^ (row&15)] = chunk j (b128 units)

    const int t = threadIdx.x;
    const int wave = t >> 6;
    const int lane = t & 63;
    const int l15 = lane & 15;
    const int quad = lane >> 4;
    const int n0 = wave * 64;
    const int half = wave >> 1;            // 0 -> s-table cols, 1 -> d-table cols
    const int colbase = n0 - half * 128;   // col within destination table

    // ---- Per-block constants: B fragments (16 x 16B, L2-hot) + bias ----
    frag_cast bfr[4][4];
#pragma unroll
    for (int s = 0; s < 4; ++s)
#pragma unroll
        for (int nt = 0; nt < 4; ++nt)
            bfr[s][nt].u = *(const uint4*)(bsw + ((s * 4 + quad) * 256 + n0 + nt * 16 + l15) * 8);

    float bias[4] = {0.f, 0.f, 0.f, 0.f};
    if (half) {
#pragma unroll
        for (int nt = 0; nt < 4; ++nt)
            bias[nt] = b1[colbase + nt * 16 + l15];
    }

    // Staging source offsets (lane-constant across tiles):
    // iter i: lds linear = (wave*4+i)*1024 + lane*16  -> (row = (wave*4+i)*2 + (lane>>5), j = lane&31)
    // source chunk = j ^ (row & 15)
    int src_off[4];
    int lds_off[4];
#pragma unroll
    for (int i = 0; i < 4; ++i) {
        const int r = (wave * 4 + i) * 2 + (lane >> 5);
        const int jsrc = (lane & 31) ^ (r & 15);
        src_off[i] = r * H + jsrc * 4;        // in floats
        lds_off[i] = (wave * 4 + i) * 256;    // in floats (1024 B)
    }

    for (int tile = blockIdx.x; tile < 2 * TILES_PER_Z; tile += gridDim.x) {
        const int zsel = tile & 1;
        const int node0 = (tile >> 1) * MT;
        const float* __restrict__ ztile =
            (zsel ? zo : zp) + (size_t)node0 * H;

        // ---- Stage A: 16 global_load_lds_dwordx4 across block (16 KB) ----
#pragma unroll
        for (int i = 0; i < 4; ++i) {
            const float* gp = ztile + src_off[i];
            float* lp = abuf + lds_off[i];
            __builtin_amdgcn_global_load_lds(
                (const __attribute__((address_space(1))) uint32_t*)gp,
                (__attribute__((address_space(3))) uint32_t*)lp, 16, 0, 0);
        }
        __syncthreads();  // drain DMA (vmcnt) + barrier

        // ---- Compute: rows 0..31 (2 mt), cols n0..n0+63 (4 nt), K=128 (4 s) ----
        f32x4 acc[2][4];
#pragma unroll
        for (int mt = 0; mt < 2; ++mt)
#pragma unroll
            for (int nt = 0; nt < 4; ++nt)
                acc[mt][nt] = (f32x4){0.f, 0.f, 0.f, 0.f};

#pragma unroll
        for (int s = 0; s < 4; ++s)
#pragma unroll
            for (int mt = 0; mt < 2; ++mt) {
                const int row = mt * 16 + l15;
                const int c = s * 4 + quad;  // 32B chunk = b128 units 2c, 2c+1
                const float4 vlo = *(const float4*)(abuf + row * H + ((2 * c) ^ l15) * 4);
                const float4 vhi = *(const float4*)(abuf + row * H + ((2 * c + 1) ^ l15) * 4);
                frag_cast a;
                a.s[0] = f2bf(vlo.x); a.s[1] = f2bf(vlo.y);
                a.s[2] = f2bf(vlo.z); a.s[3] = f2bf(vlo.w);
                a.s[4] = f2bf(vhi.x); a.s[5] = f2bf(vhi.y);
                a.s[6] = f2bf(vhi.z); a.s[7] = f2bf(vhi.w);
#pragma unroll
                for (int nt = 0; nt < 4; ++nt)
                    acc[mt][nt] = __builtin_amdgcn_mfma_f32_16x16x32_bf16(
                        a.b, bfr[s][nt].b, acc[mt][nt], 0, 0, 0);
            }
        __syncthreads();  // all ds_reads done; next staging may overwrite LDS

        // ---- Epilogue: direct stores (D: col=l15, row=quad*4+reg) ----
        ushort* __restrict__ dst =
            zsel ? (half ? t_od : t_os) : (half ? t_pd : t_ps);
#pragma unroll
        for (int mt = 0; mt < 2; ++mt)
#pragma unroll
            for (int nt = 0; nt < 4; ++nt) {
                const int col = colbase + nt * 16 + l15;
#pragma unroll
                for (int r = 0; r < 4; ++r) {
                    const int grow = node0 + mt * 16 + quad * 4 + r;
                    dst[(size_t)grow * H + col] = f2bf(acc[mt][nt][r] + bias[nt]);
                }
            }
    }
}

// 16 lanes per edge; each lane handles 8 channels (16B bf16 loads).
__global__ __launch_bounds__(256) void edge_kernel(
    const __hip_bfloat16* __restrict__ t_ps, const __hip_bfloat16* __restrict__ t_pd,
    const __hip_bfloat16* __restrict__ t_os, const __hip_bfloat16* __restrict__ t_od,
    const int* __restrict__ ptnp, const int* __restrict__ nptp,
    const int* __restrict__ nptnp,
    const float* __restrict__ w2, const float* __restrict__ b2,
    float* __restrict__ out) {
    const int tid = blockIdx.x * 256 + threadIdx.x;
    const int g = tid >> 4;        // edge id 0..3E-1
    const int lane = tid & 15;

    const __hip_bfloat16 *src_tbl, *dst_tbl;
    int si, di;
    if (g < NEDGE) {
        si = ptnp[g]; di = ptnp[NEDGE + g];
        src_tbl = t_ps; dst_tbl = t_od;
    } else if (g < 2 * NEDGE) {
        const int e = g - NEDGE;
        si = nptp[e]; di = nptp[NEDGE + e];
        src_tbl = t_os; dst_tbl = t_pd;
    } else {
        const int e = g - 2 * NEDGE;
        si = nptnp[e]; di = nptnp[NEDGE + e];
        src_tbl = t_os; dst_tbl = t_od;
    }

    const uint4 s4 = *(const uint4*)(src_tbl + si * H + lane * 8);
    const uint4 d4 = *(const uint4*)(dst_tbl + di * H + lane * 8);
    const float4 w2a = *(const float4*)(w2 + lane * 8);
    const float4 w2b = *(const float4*)(w2 + lane * 8 + 4);

    float s0, s1, d0, d1;
    float sum = 0.f;
    bf2_to_f(s4.x, s0, s1); bf2_to_f(d4.x, d0, d1);
    sum = fmaf(fmaxf(s0 + d0, 0.f), w2a.x, sum);
    sum = fmaf(fmaxf(s1 + d1, 0.f), w2a.y, sum);
    bf2_to_f(s4.y, s0, s1); bf2_to_f(d4.y, d0, d1);
    sum = fmaf(fmaxf(s0 + d0, 0.f), w2a.z, sum);
    sum = fmaf(fmaxf(s1 + d1, 0.f), w2a.w, sum);
    bf2_to_f(s4.z, s0, s1); bf2_to_f(d4.z, d0, d1);
    sum = fmaf(fmaxf(s0 + d0, 0.f), w2b.x, sum);
    sum = fmaf(fmaxf(s1 + d1, 0.f), w2b.y, sum);
    bf2_to_f(s4.w, s0, s1); bf2_to_f(d4.w, d0, d1);
    sum = fmaf(fmaxf(s0 + d0, 0.f), w2b.z, sum);
    sum = fmaf(fmaxf(s1 + d1, 0.f), w2b.w, sum);

    sum += __shfl_down(sum, 8, 16);
    sum += __shfl_down(sum, 4, 16);
    sum += __shfl_down(sum, 2, 16);
    sum += __shfl_down(sum, 1, 16);
    if (lane == 0) out[g] = sum + b2[0];
}

// Fallback (only if ws_size is too small): direct per-edge compute, fp32.
__global__ __launch_bounds__(128) void edge_direct(
    const float* __restrict__ zp, const float* __restrict__ zo,
    const int* __restrict__ ptnp, const int* __restrict__ nptp,
    const int* __restrict__ nptnp,
    const float* __restrict__ w1, const float* __restrict__ b1,
    const float* __restrict__ w2, const float* __restrict__ b2,
    float* __restrict__ out) {
    const int g = blockIdx.x;
    const int j = threadIdx.x;

    const float *src, *dst;
    int si, di;
    if (g < NEDGE) {
        si = ptnp[g]; di = ptnp[NEDGE + g]; src = zp; dst = zo;
    } else if (g < 2 * NEDGE) {
        const int e = g - NEDGE;
        si = nptp[e]; di = nptp[NEDGE + e]; src = zo; dst = zp;
    } else {
        const int e = g - 2 * NEDGE;
        si = nptnp[e]; di = nptnp[NEDGE + e]; src = zo; dst = zo;
    }
    const float* zs = src + si * H;
    const float* zd = dst + di * H;

    float acc = b1[j];
    for (int k = 0; k < H; ++k) acc = fmaf(zs[k], w1[k * H + j], acc);
    for (int k = 0; k < H; ++k) acc = fmaf(zd[k], w1[(H + k) * H + j], acc);
    float v = fmaxf(acc, 0.f) * w2[j];

    for (int off = 32; off > 0; off >>= 1) v += __shfl_down(v, off, 64);
    __shared__ float parts[2];
    if ((j & 63) == 0) parts[j >> 6] = v;
    __syncthreads();
    if (j == 0) out[g] = parts[0] + parts[1] + b2[0];
}

extern "C" void kernel_launch(void* const* d_in, const int* in_sizes, int n_in,
                              void* d_out, int out_size, void* d_ws, size_t ws_size,
                              hipStream_t stream) {
    const float* zp    = (const float*)d_in[0];
    const float* zo    = (const float*)d_in[1];
    const int*   ptnp  = (const int*)d_in[2];
    const int*   nptp  = (const int*)d_in[3];
    const int*   nptnp = (const int*)d_in[4];
    const float* w1    = (const float*)d_in[5];
    const float* b1    = (const float*)d_in[6];
    const float* w2    = (const float*)d_in[7];
    const float* b2    = (const float*)d_in[8];
    float* out = (float*)d_out;

    if (ws_size < WS_NEEDED) {
        edge_direct<<<3 * NEDGE, 128, 0, stream>>>(zp, zo, ptnp, nptp, nptnp,
                                                   w1, b1, w2, b2, out);
        return;
    }

    char* ws = (char*)d_ws;
    ushort* bsw = (ushort*)ws;
    ushort* t_ps = (ushort*)(ws + BSW_BYTES);
    ushort* t_pd = t_ps + TBL_ELEMS;
    ushort* t_os = t_pd + TBL_ELEMS;
    ushort* t_od = t_os + TBL_ELEMS;

    prep_bsw<<<128, 256, 0, stream>>>(w1, bsw);

    gemm_tables<<<GEMM_GRID, 256, 0, stream>>>(
        zp, zo, bsw, b1, t_ps, t_pd, t_os, t_od);

    const int total_threads = 3 * NEDGE * 16;
    edge_kernel<<<total_threads / 256, 256, 0, stream>>>(
        (const __hip_bfloat16*)t_ps, (const __hip_bfloat16*)t_pd,
        (const __hip_bfloat16*)t_os, (const __hip_bfloat16*)t_od,
        ptnp, nptp, nptnp, w2, b2, out);
}